// Round 1
// baseline (4250.456 us; speedup 1.0000x reference)
//
#include <hip/hip_runtime.h>
#include <hip/hip_bf16.h>
#include <stdint.h>

// Problem constants (from reference): B=512, S=512, F=64, H=128, 4H=512, O=64
#define HID 128
#define SEQ 512
#define BATCH 512
#define GATES 512   // 4*HID
#define NB 2        // batch elements per block

__device__ __forceinline__ float sigmoid_f(float x) {
    // safe at extremes: x<<0 -> exp(+big)=inf -> 0; x>>0 -> 1/(1+0)=1
    return 1.0f / (1.0f + __expf(-x));
}
__device__ __forceinline__ float tanh_f(float x) {
    // 1 - 2/(e^{2x}+1): saturates to +/-1 without inf/inf
    return 1.0f - 2.0f / (__expf(2.0f * x) + 1.0f);
}

__device__ __forceinline__ uint32_t bf16_rne(float f) {
    uint32_t u = __float_as_uint(f);
    return (u + 0x7fffu + ((u >> 16) & 1u)) >> 16;
}

// ---------------- Layer 0 ----------------
// x: [B, S, 64]; Wih: [512,64]; Whh: [512,128]; out hseq: [B, S, 128] (fp32, in ws)
// 512 threads: thread g owns gate row g (weights in VGPRs). NB=2 batch/block.
__global__ __launch_bounds__(512, 2) void lstm_layer0(
    const float* __restrict__ x, const float* __restrict__ Wih,
    const float* __restrict__ Whh, const float* __restrict__ bih,
    const float* __restrict__ bhh, float* __restrict__ hseq)
{
    const int g  = threadIdx.x;
    const int bb = blockIdx.x * NB;

    // register-resident weights: 16 + 32 float4 = 192 VGPR
    float4 wih[16], whh[32];
    const float4* pih = (const float4*)(Wih + g * 64);
#pragma unroll
    for (int i = 0; i < 16; i++) wih[i] = pih[i];
    const float4* phh = (const float4*)(Whh + g * HID);
#pragma unroll
    for (int i = 0; i < 32; i++) whh[i] = phh[i];
    const float bias = bih[g] + bhh[g];

    __shared__ float xl[NB][64];
    __shared__ float hl[NB][HID];
    __shared__ float ga[NB][GATES];

    if (g < NB * HID) hl[g >> 7][g & 127] = 0.0f;
    if (g < NB * 64) {
        int b = g >> 6, f = g & 63;
        xl[b][f] = x[(size_t)(bb + b) * SEQ * 64 + f];  // t=0
    }
    float c0 = 0.0f;  // cell state for thread (b = g>>7, j = g&127), g < 256
    __syncthreads();

    for (int t = 0; t < SEQ; t++) {
        // ---- gates: acc_b = bias + Wih.x_t + Whh.h  (uniform-address LDS broadcasts)
        float acc0 = bias, acc1 = bias;
#pragma unroll
        for (int k = 0; k < 16; k++) {
            float4 xa = ((const float4*)xl[0])[k];
            float4 xb = ((const float4*)xl[1])[k];
            acc0 += wih[k].x * xa.x + wih[k].y * xa.y + wih[k].z * xa.z + wih[k].w * xa.w;
            acc1 += wih[k].x * xb.x + wih[k].y * xb.y + wih[k].z * xb.z + wih[k].w * xb.w;
        }
#pragma unroll
        for (int k = 0; k < 32; k++) {
            float4 ha = ((const float4*)hl[0])[k];
            float4 hb = ((const float4*)hl[1])[k];
            acc0 += whh[k].x * ha.x + whh[k].y * ha.y + whh[k].z * ha.z + whh[k].w * ha.w;
            acc1 += whh[k].x * hb.x + whh[k].y * hb.y + whh[k].z * hb.z + whh[k].w * hb.w;
        }
        // activation: gate class 0,1,3 sigmoid (i,f,o); class 2 tanh (g)
        if ((g >> 7) == 2) { acc0 = tanh_f(acc0); acc1 = tanh_f(acc1); }
        else              { acc0 = sigmoid_f(acc0); acc1 = sigmoid_f(acc1); }
        ga[0][g] = acc0;
        ga[1][g] = acc1;
        __syncthreads();

        // ---- state update (threads 0..255) + x prefetch (threads 256..383)
        if (g < NB * HID) {
            int b = g >> 7, j = g & 127;
            float i_ = ga[b][j], f_ = ga[b][HID + j], g_ = ga[b][2 * HID + j], o_ = ga[b][3 * HID + j];
            c0 = f_ * c0 + i_ * g_;
            float h = o_ * tanh_f(c0);
            hl[b][j] = h;
            hseq[(size_t)(bb + b) * SEQ * HID + (size_t)t * HID + j] = h;
        } else if (g < NB * HID + NB * 64 && t + 1 < SEQ) {
            int idx = g - NB * HID, b = idx >> 6, f = idx & 63;
            xl[b][f] = x[(size_t)(bb + b) * SEQ * 64 + (size_t)(t + 1) * 64 + f];
        }
        __syncthreads();
    }
}

// ---------------- Layer 1 ----------------
// input hseq: [B, S, 128]; Wih: [512,128] (bf16-packed in regs); Whh: [512,128] fp32 regs.
// writes only h_last [B,128].
__global__ __launch_bounds__(512, 2) void lstm_layer1(
    const float* __restrict__ hseq, const float* __restrict__ Wih,
    const float* __restrict__ Whh, const float* __restrict__ bih,
    const float* __restrict__ bhh, float* __restrict__ h_last)
{
    const int g  = threadIdx.x;
    const int bb = blockIdx.x * NB;

    // W_ih1 row packed bf16: 64 u32 regs; W_hh1 fp32: 32 float4 regs
    uint32_t wihp[64];
    {
        const float4* p = (const float4*)(Wih + g * HID);
#pragma unroll
        for (int i = 0; i < 32; i++) {
            float4 v = p[i];
            wihp[2 * i]     = bf16_rne(v.x) | (bf16_rne(v.y) << 16);
            wihp[2 * i + 1] = bf16_rne(v.z) | (bf16_rne(v.w) << 16);
        }
    }
    float4 whh[32];
    const float4* phh = (const float4*)(Whh + g * HID);
#pragma unroll
    for (int i = 0; i < 32; i++) whh[i] = phh[i];
    const float bias = bih[g] + bhh[g];

    __shared__ float xl[NB][HID];
    __shared__ float hl[NB][HID];
    __shared__ float ga[NB][GATES];

    if (g < NB * HID) {
        int b = g >> 7, f = g & 127;
        hl[b][f] = 0.0f;
        xl[b][f] = hseq[(size_t)(bb + b) * SEQ * HID + f];  // t=0
    }
    float c0 = 0.0f;
    __syncthreads();

    for (int t = 0; t < SEQ; t++) {
        float acc0 = bias, acc1 = bias;
#pragma unroll
        for (int k = 0; k < 32; k++) {  // input-projection part, bf16 weights
            float4 xa = ((const float4*)xl[0])[k];
            float4 xb = ((const float4*)xl[1])[k];
            float w0 = __uint_as_float(wihp[2 * k] << 16);
            float w1 = __uint_as_float(wihp[2 * k] & 0xffff0000u);
            float w2 = __uint_as_float(wihp[2 * k + 1] << 16);
            float w3 = __uint_as_float(wihp[2 * k + 1] & 0xffff0000u);
            acc0 += w0 * xa.x + w1 * xa.y + w2 * xa.z + w3 * xa.w;
            acc1 += w0 * xb.x + w1 * xb.y + w2 * xb.z + w3 * xb.w;
        }
#pragma unroll
        for (int k = 0; k < 32; k++) {  // recurrent part, fp32 weights
            float4 ha = ((const float4*)hl[0])[k];
            float4 hb = ((const float4*)hl[1])[k];
            acc0 += whh[k].x * ha.x + whh[k].y * ha.y + whh[k].z * ha.z + whh[k].w * ha.w;
            acc1 += whh[k].x * hb.x + whh[k].y * hb.y + whh[k].z * hb.z + whh[k].w * hb.w;
        }
        if ((g >> 7) == 2) { acc0 = tanh_f(acc0); acc1 = tanh_f(acc1); }
        else              { acc0 = sigmoid_f(acc0); acc1 = sigmoid_f(acc1); }
        ga[0][g] = acc0;
        ga[1][g] = acc1;
        __syncthreads();

        if (g < NB * HID) {
            int b = g >> 7, j = g & 127;
            float i_ = ga[b][j], f_ = ga[b][HID + j], g_ = ga[b][2 * HID + j], o_ = ga[b][3 * HID + j];
            c0 = f_ * c0 + i_ * g_;
            float h = o_ * tanh_f(c0);
            hl[b][j] = h;
            if (t == SEQ - 1) h_last[(bb + b) * HID + j] = h;
        } else if (g < 2 * NB * HID && t + 1 < SEQ) {
            int idx = g - NB * HID, b = idx >> 7, f = idx & 127;
            xl[b][f] = hseq[(size_t)(bb + b) * SEQ * HID + (size_t)(t + 1) * HID + f];
        }
        __syncthreads();
    }
}

// ---------------- FC head ----------------
// out[b][o] = relu(h1[b,:]) . fc_w[o,:] + fc_b[o];  B=512, O=64, K=128
__global__ void fc_kernel(const float* __restrict__ h1, const float* __restrict__ fcw,
                          const float* __restrict__ fcb, float* __restrict__ out)
{
    int id = blockIdx.x * 256 + threadIdx.x;  // 32768 = 512*64
    int b = id >> 6, o = id & 63;
    const float4* h4 = (const float4*)(h1 + b * HID);
    const float4* w4 = (const float4*)(fcw + o * HID);
    float acc = fcb[o];
#pragma unroll
    for (int k = 0; k < 32; k++) {
        float4 hv = h4[k], wv = w4[k];
        acc += fmaxf(hv.x, 0.0f) * wv.x + fmaxf(hv.y, 0.0f) * wv.y +
               fmaxf(hv.z, 0.0f) * wv.z + fmaxf(hv.w, 0.0f) * wv.w;
    }
    out[id] = acc;
}

extern "C" void kernel_launch(void* const* d_in, const int* in_sizes, int n_in,
                              void* d_out, int out_size, void* d_ws, size_t ws_size,
                              hipStream_t stream) {
    const float* x    = (const float*)d_in[0];
    const float* Wih0 = (const float*)d_in[1];
    const float* Whh0 = (const float*)d_in[2];
    const float* bih0 = (const float*)d_in[3];
    const float* bhh0 = (const float*)d_in[4];
    const float* Wih1 = (const float*)d_in[5];
    const float* Whh1 = (const float*)d_in[6];
    const float* bih1 = (const float*)d_in[7];
    const float* bhh1 = (const float*)d_in[8];
    const float* fcw  = (const float*)d_in[9];
    const float* fcb  = (const float*)d_in[10];

    // ws layout: h0_seq fp32 [512][512][128] = 64 MB, then h1_last [512][128] = 256 KB
    float* hseq = (float*)d_ws;
    float* h1   = hseq + (size_t)BATCH * SEQ * HID;

    lstm_layer0<<<BATCH / NB, 512, 0, stream>>>(x, Wih0, Whh0, bih0, bhh0, hseq);
    lstm_layer1<<<BATCH / NB, 512, 0, stream>>>(hseq, Wih1, Whh1, bih1, bhh1, h1);
    fc_kernel<<<(BATCH * 64) / 256, 256, 0, stream>>>(h1, fcw, fcb, (float*)d_out);
}

// Round 3
// 1136.703 us; speedup vs baseline: 3.7393x; 3.7393x over previous
//
#include <hip/hip_runtime.h>
#include <stdint.h>

// B=512, S=512, F=64, H=128, 4H=512, O=64
#define SEQ 512
#define HID 128

typedef short bf16x8 __attribute__((ext_vector_type(8)));   // 8 bf16 = 4 VGPR
typedef float f32x4v __attribute__((ext_vector_type(4)));   // MFMA acc

#define MFMA16(a, b, c) __builtin_amdgcn_mfma_f32_16x16x32_bf16((a), (b), (c), 0, 0, 0)

__device__ __forceinline__ uint32_t bfr(float f) {          // fp32 -> bf16 (RNE)
    uint32_t u = __float_as_uint(f);
    return (u + 0x7fffu + ((u >> 16) & 1u)) >> 16;
}
__device__ __forceinline__ uint32_t bfp(float a, float b) { // pack 2 bf16
    return bfr(a) | (bfr(b) << 16);
}
__device__ __forceinline__ float fsig(float x) {
    return __builtin_amdgcn_rcpf(1.0f + __expf(-x));
}
__device__ __forceinline__ float ftanh(float x) {
    return 1.0f - 2.0f * __builtin_amdgcn_rcpf(__expf(2.0f * x) + 1.0f);
}

// A-fragment: lane holds W[rowbase + (lane&15)][k0 .. k0+7] as bf16x8.
__device__ __forceinline__ bf16x8 afrag(const float* W, int row, int K, int k0) {
    const float4* p = (const float4*)(W + (size_t)row * K + k0);
    float4 a = p[0], b = p[1];
    union { bf16x8 v; uint32_t u[4]; } f;
    f.u[0] = bfp(a.x, a.y); f.u[1] = bfp(a.z, a.w);
    f.u[2] = bfp(b.x, b.y); f.u[3] = bfp(b.z, b.w);
    return f.v;
}

// ============================ Layer 0 ============================
// Per block: 16 batch rows. Gates[512,16] = Wih0@[x_hi;x_lo] + Whh0@h + bias.
// Wave w owns gate rows {c*128 + 16w .. +16} for c=0..3  ->  i,f,g,o for the
// same j live in one lane's 4 accumulators -> in-register c/h update.
// Writes h0_seq to ws as bf16 in B-fragment granule layout:
//   elem(t, bblk, jblk, b, ji) at (((t*32+bblk)*16 + jblk)*16 + b)*8 + ji
__global__ __launch_bounds__(512, 2) void lstm_l0(
    const float* __restrict__ x, const float* __restrict__ Wih,
    const float* __restrict__ Whh, const float* __restrict__ bih,
    const float* __restrict__ bhh, unsigned short* __restrict__ hseq)
{
    const int tid = threadIdx.x;
    const int wid = tid >> 6, lane = tid & 63;
    const int l15 = lane & 15, lg = lane >> 4;
    const int bblk = blockIdx.x, bb = bblk * 16;
    const int jb = wid * 16;

    __shared__ __align__(16) uint8_t lds[16384];
    uint8_t* hbuf = lds;            // 2 x 4096: h[b][j] bf16, row 256B, XOR-swizzled
    uint8_t* xbuf = lds + 8192;     // 2 par x (hi 2KB + lo 2KB): x[b][f] bf16, row 128B

    // ---- weights -> registers (bf16 A-fragments), bias -> f32
    bf16x8 wih[4][2], whh[4][4];
    f32x4v bias[4];
#pragma unroll
    for (int c = 0; c < 4; c++) {
        int row = c * 128 + jb + l15;
#pragma unroll
        for (int kt = 0; kt < 2; kt++) wih[c][kt] = afrag(Wih, row, 64, kt * 32 + lg * 8);
#pragma unroll
        for (int kt = 0; kt < 4; kt++) whh[c][kt] = afrag(Whh, row, 128, kt * 32 + lg * 8);
#pragma unroll
        for (int e = 0; e < 4; e++) {
            int gr = c * 128 + jb + lg * 4 + e;
            bias[c][e] = bih[gr] + bhh[gr];
        }
    }

    // ---- init: zero h (both parities), stage x(t=0) into parity 0
    *(f32x4v*)(lds + tid * 16) = f32x4v{0.f, 0.f, 0.f, 0.f};   // covers hbuf 8KB
    const int xrb = tid >> 5, xf0 = (tid & 31) * 2;
    const size_t xbase = (size_t)(bb + xrb) * SEQ * 64 + xf0;
    {
        float2 v = *(const float2*)(x + xbase);
        uint32_t hx = bfr(v.x), hy = bfr(v.y);
        float rx = v.x - __uint_as_float(hx << 16);
        float ry = v.y - __uint_as_float(hy << 16);
        int kb = (2 * xf0) ^ ((xrb & 7) << 4);
        *(uint32_t*)(xbuf + xrb * 128 + kb) = hx | (hy << 16);
        *(uint32_t*)(xbuf + 2048 + xrb * 128 + kb) = bfr(rx) | (bfr(ry) << 16);
    }
    __syncthreads();

    float cst[4] = {0.f, 0.f, 0.f, 0.f};
    const int j0 = jb + lg * 4;
    const int hwb = l15 * 256 + ((2 * j0) ^ ((l15 & 7) << 4));   // h LDS write byte
    const int swz = (l15 & 7) << 4;

    for (int t = 0; t < SEQ; t++) {
        // prefetch x(t+1) (consumed at end of this step)
        float2 xv = {0.f, 0.f};
        if (t + 1 < SEQ) xv = *(const float2*)(x + xbase + (size_t)(t + 1) * 64);

        // ---- B-fragments from LDS (2-way conflict = free)
        const uint8_t* hb = hbuf + (t & 1) * 4096;
        const uint8_t* xh = xbuf + (t & 1) * 4096;
        bf16x8 xhf[2], xlf[2], hf[4];
#pragma unroll
        for (int kt = 0; kt < 2; kt++) {
            int kb = (2 * (kt * 32 + lg * 8)) ^ swz;
            xhf[kt] = *(const bf16x8*)(xh + l15 * 128 + kb);
            xlf[kt] = *(const bf16x8*)(xh + 2048 + l15 * 128 + kb);
        }
#pragma unroll
        for (int kt = 0; kt < 4; kt++) {
            int kb = (2 * (kt * 32 + lg * 8)) ^ swz;
            hf[kt] = *(const bf16x8*)(hb + l15 * 256 + kb);
        }

        // ---- MFMA: acc[c] = bias + Wih@(x_hi+x_lo) + Whh@h
        f32x4v acc[4];
#pragma unroll
        for (int c = 0; c < 4; c++) {
            f32x4v a = MFMA16(wih[c][0], xhf[0], bias[c]);
            a = MFMA16(wih[c][1], xhf[1], a);
            a = MFMA16(wih[c][0], xlf[0], a);
            a = MFMA16(wih[c][1], xlf[1], a);
#pragma unroll
            for (int kt = 0; kt < 4; kt++) a = MFMA16(whh[c][kt], hf[kt], a);
            acc[c] = a;
        }

        // ---- in-register activations + c/h update (lane owns (b=l15, j0..j0+3))
        float h[4];
#pragma unroll
        for (int e = 0; e < 4; e++) {
            float ig = fsig(acc[0][e]);
            float fg = fsig(acc[1][e]);
            float gg = ftanh(acc[2][e]);
            float og = fsig(acc[3][e]);
            float cv = fg * cst[e] + ig * gg;
            cst[e] = cv;
            h[e] = og * ftanh(cv);
        }
        uint32_t hp0 = bfp(h[0], h[1]), hp1 = bfp(h[2], h[3]);

        // stage x(t+1) into other parity
        if (t + 1 < SEQ) {
            uint8_t* xn = xbuf + ((t + 1) & 1) * 4096;
            uint32_t hx = bfr(xv.x), hy = bfr(xv.y);
            float rx = xv.x - __uint_as_float(hx << 16);
            float ry = xv.y - __uint_as_float(hy << 16);
            int kb = (2 * xf0) ^ ((xrb & 7) << 4);
            *(uint32_t*)(xn + xrb * 128 + kb) = hx | (hy << 16);
            *(uint32_t*)(xn + 2048 + xrb * 128 + kb) = bfr(rx) | (bfr(ry) << 16);
        }

        // write h: LDS other parity + global (B-frag layout, fully coalesced)
        *(uint2*)(hbuf + ((t + 1) & 1) * 4096 + hwb) = make_uint2(hp0, hp1);
        {
            int gidx = (((t * 32 + bblk) * 16 + (j0 >> 3)) * 16 + l15) * 8 + (j0 & 7);
            *(uint2*)(hseq + gidx) = make_uint2(hp0, hp1);
        }
        __syncthreads();
    }
}

// ============================ Layer 1 + FC ============================
__global__ __launch_bounds__(512, 2) void lstm_l1_fc(
    const unsigned short* __restrict__ hseq, const float* __restrict__ Wih,
    const float* __restrict__ Whh, const float* __restrict__ bih,
    const float* __restrict__ bhh, const float* __restrict__ fcw,
    const float* __restrict__ fcb, float* __restrict__ out)
{
    const int tid = threadIdx.x;
    const int wid = tid >> 6, lane = tid & 63;
    const int l15 = lane & 15, lg = lane >> 4;
    const int bblk = blockIdx.x, bb = bblk * 16;
    const int jb = wid * 16;

    __shared__ __align__(16) uint8_t lds[16384];
    uint8_t* h1b = lds;                    // 2 x 4096 h1 dbuf (swizzled bf16)
    float* hfin = (float*)(lds + 8192);    // [16][128] f32 final h1

    bf16x8 wih[4][4], whh[4][4];
    f32x4v bias[4];
#pragma unroll
    for (int c = 0; c < 4; c++) {
        int row = c * 128 + jb + l15;
#pragma unroll
        for (int kt = 0; kt < 4; kt++) {
            wih[c][kt] = afrag(Wih, row, 128, kt * 32 + lg * 8);
            whh[c][kt] = afrag(Whh, row, 128, kt * 32 + lg * 8);
        }
#pragma unroll
        for (int e = 0; e < 4; e++) {
            int gr = c * 128 + jb + lg * 4 + e;
            bias[c][e] = bih[gr] + bhh[gr];
        }
    }

    *(f32x4v*)(lds + tid * 16) = f32x4v{0.f, 0.f, 0.f, 0.f};   // zero h1 dbuf
    __syncthreads();

    float cst[4] = {0.f, 0.f, 0.f, 0.f};
    const int j0 = jb + lg * 4;
    const int hwb = l15 * 256 + ((2 * j0) ^ ((l15 & 7) << 4));
    const int swz = (l15 & 7) << 4;

    // h0 B-fragments from ws: granule layout written by lstm_l0
    bf16x8 h0f[2][4];
#pragma unroll
    for (int kt = 0; kt < 4; kt++) {
        int g = ((0 * 32 + bblk) * 16 + (kt * 4 + lg)) * 16 + l15;
        h0f[0][kt] = *(const bf16x8*)(hseq + g * 8);
    }

    for (int tp = 0; tp < SEQ / 2; tp++) {
#pragma unroll
        for (int ph = 0; ph < 2; ph++) {                 // manual unroll-2: static reg parity
            const int t = 2 * tp + ph;
            if (t + 1 < SEQ) {                           // prefetch h0(t+1)
#pragma unroll
                for (int kt = 0; kt < 4; kt++) {
                    int g = (((t + 1) * 32 + bblk) * 16 + (kt * 4 + lg)) * 16 + l15;
                    h0f[ph ^ 1][kt] = *(const bf16x8*)(hseq + g * 8);
                }
            }
            const uint8_t* hb = h1b + (t & 1) * 4096;
            bf16x8 h1f[4];
#pragma unroll
            for (int kt = 0; kt < 4; kt++) {
                int kb = (2 * (kt * 32 + lg * 8)) ^ swz;
                h1f[kt] = *(const bf16x8*)(hb + l15 * 256 + kb);
            }

            f32x4v acc[4];
#pragma unroll
            for (int c = 0; c < 4; c++) {
                f32x4v a = MFMA16(wih[c][0], h0f[ph][0], bias[c]);
#pragma unroll
                for (int kt = 1; kt < 4; kt++) a = MFMA16(wih[c][kt], h0f[ph][kt], a);
#pragma unroll
                for (int kt = 0; kt < 4; kt++) a = MFMA16(whh[c][kt], h1f[kt], a);
                acc[c] = a;
            }

            float h[4];
#pragma unroll
            for (int e = 0; e < 4; e++) {
                float ig = fsig(acc[0][e]);
                float fg = fsig(acc[1][e]);
                float gg = ftanh(acc[2][e]);
                float og = fsig(acc[3][e]);
                float cv = fg * cst[e] + ig * gg;
                cst[e] = cv;
                h[e] = og * ftanh(cv);
            }
            *(uint2*)(h1b + ((t + 1) & 1) * 4096 + hwb) = make_uint2(bfp(h[0], h[1]), bfp(h[2], h[3]));
            if (t == SEQ - 1)
                *(f32x4v*)(hfin + l15 * HID + j0) = f32x4v{h[0], h[1], h[2], h[3]};
            __syncthreads();
        }
    }

    // ---- fused FC: out[b][o] = relu(h1).fcw[o] + fcb[o]
    const int fb = tid >> 5, op = (tid & 31) * 2;
    float a0 = fcb[op], a1 = fcb[op + 1];
    const float4* w0 = (const float4*)(fcw + op * HID);
    const float4* w1 = (const float4*)(fcw + (op + 1) * HID);
    const float4* hv4 = (const float4*)(hfin + fb * HID);
#pragma unroll 8
    for (int k = 0; k < 32; k++) {
        float4 hv = hv4[k];
        float r0 = fmaxf(hv.x, 0.f), r1 = fmaxf(hv.y, 0.f);
        float r2 = fmaxf(hv.z, 0.f), r3 = fmaxf(hv.w, 0.f);
        float4 wa = w0[k], wb = w1[k];
        a0 += r0 * wa.x + r1 * wa.y + r2 * wa.z + r3 * wa.w;
        a1 += r0 * wb.x + r1 * wb.y + r2 * wb.z + r3 * wb.w;
    }
    out[(bb + fb) * 64 + op] = a0;
    out[(bb + fb) * 64 + op + 1] = a1;
}

extern "C" void kernel_launch(void* const* d_in, const int* in_sizes, int n_in,
                              void* d_out, int out_size, void* d_ws, size_t ws_size,
                              hipStream_t stream) {
    const float* x    = (const float*)d_in[0];
    const float* Wih0 = (const float*)d_in[1];
    const float* Whh0 = (const float*)d_in[2];
    const float* bih0 = (const float*)d_in[3];
    const float* bhh0 = (const float*)d_in[4];
    const float* Wih1 = (const float*)d_in[5];
    const float* Whh1 = (const float*)d_in[6];
    const float* bih1 = (const float*)d_in[7];
    const float* bhh1 = (const float*)d_in[8];
    const float* fcw  = (const float*)d_in[9];
    const float* fcb  = (const float*)d_in[10];

    // ws: h0_seq bf16 in B-fragment granule layout, 64 MiB
    unsigned short* hseq = (unsigned short*)d_ws;

    lstm_l0<<<32, 512, 0, stream>>>(x, Wih0, Whh0, bih0, bhh0, hseq);
    lstm_l1_fc<<<32, 512, 0, stream>>>(hseq, Wih1, Whh1, bih1, bhh1, fcw, fcb, (float*)d_out);
}